// Round 10
// baseline (512.961 us; speedup 1.0000x reference)
//
#include <hip/hip_runtime.h>
#include <hip/hip_bf16.h>

// EncoderAttention4 v11: v10 + phase-7 register re-budget (spill elimination).
// B=65536, NEGO=48, NADO=24, NADOAG=5, E=256, H=4, AD=64. Out: (B,112) fp32.
//
// v10 post-mortem: NT loads cut FETCH 59->38MB, dur flat -> L3-latency theory
// dead. The real tell: WRITE_SIZE 229MB vs ideal 31MB on EVERY 512-thread
// variant (v2's 256-thr/256-reg config wrote a clean 30MB). ~200MB = ~25 f32
// scratch-spill slots/thread: at 16 waves/CU the unified RF gives 128/wave,
// ~64 to AGPR accumulators, and phase 7's VALU live set (~90) overflows.
// v11 cuts phase-7 live state under the 64-VGPR envelope:
//  - key/lat passes agent-grouped (3+2): kacc[3]+af[3]=24 live vs 40
//    (costs 1 extra B-load per (c2,kb) per pass; ~32 extra L2 loads/wave)
//  - softmax in-place in part[] (no separate p[5]: -20 regs at the seam)
// Everything else byte-identical to v10.

typedef __bf16 bf16x8 __attribute__((ext_vector_type(8)));
typedef __bf16 bf16x4 __attribute__((ext_vector_type(4)));
typedef float  f32x4  __attribute__((ext_vector_type(4)));

// Workspace layout (bf16 elements), unchanged.
#define OFF_EGO0 0        // [256][64]  (K=48 padded to 64)
#define OFF_EGO1 16384    // [256][256]
#define OFF_ADO0 81920    // [256][32]  (K=25 padded to 32)
#define OFF_ADO1 90112    // [256][256]
#define OFF_SEL  155648   // [256][256] col c -> head c>>6, d c&63
#define OFF_KEY  221184
#define OFF_LAT  286720
#define OFF_PROJ 352256   // [64][256]
#define WS_ELEMS 368640

__global__ __launch_bounds__(256) void prep_weights(
    const float* __restrict__ ew0, const float* __restrict__ ew1,
    const float* __restrict__ aw0, const float* __restrict__ aw1,
    const float* __restrict__ keyw, const float* __restrict__ selw,
    const float* __restrict__ latw, const float* __restrict__ projw,
    __bf16* __restrict__ ws)
{
  int i = blockIdx.x * 256 + threadIdx.x;
  if (i >= WS_ELEMS) return;
  float v;
  if (i < OFF_EGO1)      { int j=i;          int c=j>>6, k=j&63;  v = (k<48) ? ew0[k*256+c] : 0.f; }
  else if (i < OFF_ADO0) { int j=i-OFF_EGO1; int c=j>>8, k=j&255; v = ew1[k*256+c]; }
  else if (i < OFF_ADO1) { int j=i-OFF_ADO0; int c=j>>5, k=j&31;  v = (k<25) ? aw0[k*256+c] : 0.f; }
  else if (i < OFF_SEL)  { int j=i-OFF_ADO1; int c=j>>8, k=j&255; v = aw1[k*256+c]; }
  else if (i < OFF_KEY)  { int j=i-OFF_SEL;  int c=j>>8, k=j&255; v = selw[(c>>6)*16384 + k*64 + (c&63)]; }
  else if (i < OFF_LAT)  { int j=i-OFF_KEY;  int c=j>>8, k=j&255; v = keyw[(c>>6)*16384 + k*64 + (c&63)]; }
  else if (i < OFF_PROJ) { int j=i-OFF_LAT;  int c=j>>8, k=j&255; v = latw[(c>>6)*16384 + k*64 + (c&63)]; }
  else                   { int j=i-OFF_PROJ; int c=j>>8, k=j&255; v = projw[k*64+c]; }
  ws[i] = (__bf16)v;
}

// XOR-swizzled LDS accessors. byte ^= (row&7)<<4.
__device__ __forceinline__ bf16x8 lds_loadA(const __bf16* base, int row, int kByte, int rowBytes) {
  int off = (row * rowBytes + kByte) ^ ((row & 7) << 4);
  return *reinterpret_cast<const bf16x8*>(reinterpret_cast<const char*>(base) + off);
}
__device__ __forceinline__ void lds_store_bf16(__bf16* base, int row, int col, __bf16 v) {
  int off = (row * 512 + col * 2) ^ ((row & 7) << 4);  // 256-col tiles only
  *reinterpret_cast<__bf16*>(reinterpret_cast<char*>(base) + off) = v;
}

// LDS pool (bytes). Aliased regions with phase-disjoint lifetimes:
//   P_ADO2  [0,40960)      : ado activations, 80x512 swz (written ph4/ph6)
//     P_EGOIN [0,2048)     : ego input 16x128 swz   (dead after ph2)
//     P_EGOH1 [2048,10240) : ego hidden1 16x512 swz (dead after ph3)
//     P_ADOIN [24576,29696): ado input 80x64 swz    (dead after ph5)
//   P_EGOH2 [40960,49152)  : ego hidden2 16x512 swz (dead after ph4 'sel')
//     P_PROJIN (same addr) : proj input 16x512 swz  (written ph7)
//   P_H1    [49152,73728)  : ado hidden1 half, 48x512 swz (dead after ph6)
//     P_OBSRAW (same addr) : raw fp32 obs 16x168    (dead after ph1b)
//   P_OUT   [73728,77824)  : logit exchange (ph7) then proj fp32 out (ph8)
#define P_ADO2   0
#define P_EGOIN  0
#define P_EGOH1  2048
#define P_ADOIN  24576
#define P_EGOH2  40960
#define P_PROJIN 40960
#define P_H1     49152
#define P_OBSRAW 49152
#define P_OUT    73728
#define POOL_BYTES 77824   // 76KB -> 2 blocks/CU (152KB of 160KB)

// C(out 16R rows x 32 cols/wave) = act(A @ WT^T + bias). Column-split:
// wave w owns cols w*32 + c2*16 + lr. Each B fragment read once per block.
template<int KP, int R, bool ACT>
__device__ __forceinline__ void gemm_block(const __bf16* __restrict__ sA, int aRow0,
                                           __bf16* __restrict__ sC, int cRow0,
                                           const __bf16* __restrict__ WT,
                                           const float* __restrict__ bias,
                                           int w, int lr, int lg)
{
  constexpr int NKB = KP / 32;
  f32x4 acc[R][2];
  #pragma unroll
  for (int t = 0; t < R; ++t) {
    acc[t][0] = f32x4{0.f,0.f,0.f,0.f};
    acc[t][1] = f32x4{0.f,0.f,0.f,0.f};
  }
  #pragma unroll
  for (int kb = 0; kb < NKB; ++kb) {
    bf16x8 af[R];
    #pragma unroll
    for (int t = 0; t < R; ++t)
      af[t] = lds_loadA(sA, aRow0 + t*16 + lr, kb*64 + lg*16, KP*2);
    #pragma unroll
    for (int c2 = 0; c2 < 2; ++c2) {
      const int col = w*32 + c2*16 + lr;
      bf16x8 bfr = *reinterpret_cast<const bf16x8*>(WT + col*KP + kb*32 + lg*8);
      #pragma unroll
      for (int t = 0; t < R; ++t)
        acc[t][c2] = __builtin_amdgcn_mfma_f32_16x16x32_bf16(af[t], bfr, acc[t][c2], 0, 0, 0);
    }
  }
  #pragma unroll
  for (int c2 = 0; c2 < 2; ++c2) {
    const int col = w*32 + c2*16 + lr;
    const float bv = bias[col];
    #pragma unroll
    for (int t = 0; t < R; ++t) {
      #pragma unroll
      for (int e = 0; e < 4; ++e) {
        float x = acc[t][c2][e] + bv;
        if (ACT) x = x > 0.f ? x : 0.01f * x;
        lds_store_bf16(sC, cRow0 + t*16 + lg*4 + e, col, (__bf16)x);
      }
    }
  }
}

// Agent-grouped attention pass: NG agents starting at agent row 'base'.
// Keeps simultaneous live state at kacc[NG] + af[NG] (<= 24 regs for NG=3).
template<int NG>
__device__ __forceinline__ void attn_pass(const __bf16* __restrict__ sAdo2,
                                          const __bf16* __restrict__ WT,
                                          int base, int col,
                                          int lr, int lg,
                                          f32x4 (&acc)[NG])
{
  #pragma unroll
  for (int n = 0; n < NG; ++n) acc[n] = f32x4{0.f,0.f,0.f,0.f};
  #pragma unroll
  for (int kb = 0; kb < 8; ++kb) {
    bf16x8 af[NG];
    #pragma unroll
    for (int n = 0; n < NG; ++n)
      af[n] = lds_loadA(sAdo2, (base + n)*16 + lr, kb*64 + lg*16, 512);
    bf16x8 b = *reinterpret_cast<const bf16x8*>(WT + col*256 + kb*32 + lg*8);
    #pragma unroll
    for (int n = 0; n < NG; ++n)
      acc[n] = __builtin_amdgcn_mfma_f32_16x16x32_bf16(af[n], b, acc[n], 0, 0, 0);
  }
}

__global__ __launch_bounds__(512, 4) void fused_kernel(
    const float* __restrict__ obs,
    const float* __restrict__ eb0, const float* __restrict__ eb1,
    const float* __restrict__ ab0, const float* __restrict__ ab1,
    const float* __restrict__ latb, const float* __restrict__ projb,
    const __bf16* __restrict__ ws,
    float* __restrict__ out)
{
  const int tid = threadIdx.x;
  const int w  = tid >> 6;   // 8 waves
  const int l  = tid & 63;
  const int lr = l & 15;
  const int lg = l >> 4;
  const int b0 = blockIdx.x * 16;

  __shared__ __align__(16) char pool[POOL_BYTES];
  __bf16* sEgoIn = reinterpret_cast<__bf16*>(pool + P_EGOIN);
  __bf16* sEgoH1 = reinterpret_cast<__bf16*>(pool + P_EGOH1);
  __bf16* sAdoIn = reinterpret_cast<__bf16*>(pool + P_ADOIN);
  __bf16* sEgoH2 = reinterpret_cast<__bf16*>(pool + P_EGOH2);
  __bf16* sProj  = reinterpret_cast<__bf16*>(pool + P_PROJIN);
  __bf16* sAdo2  = reinterpret_cast<__bf16*>(pool + P_ADO2);
  __bf16* sH1    = reinterpret_cast<__bf16*>(pool + P_H1);
  float*  sObsF  = reinterpret_cast<float*>(pool + P_OBSRAW);
  float*  sLogF  = reinterpret_cast<float*>(pool + P_OUT);
  float*  sOutF  = reinterpret_cast<float*>(pool + P_OUT);

  // ---- phase 1a: NT coalesced obs -> LDS (fp32) + NT passthrough out[:, :48]
  {
    const f32x4* o4 = reinterpret_cast<const f32x4*>(obs);
    #pragma unroll
    for (int idx = tid; idx < 672; idx += 512) {   // 16 rows x 42 f32x4
      int row = idx / 42, c4 = idx % 42;
      f32x4 v = __builtin_nontemporal_load(o4 + (size_t)(b0+row)*42 + c4);
      *reinterpret_cast<f32x4*>(sObsF + row*168 + c4*4) = v;
      if (c4 < 12)
        __builtin_nontemporal_store(v,
            reinterpret_cast<f32x4*>(out + (size_t)(b0+row)*112 + c4*4));
    }
  }
  __syncthreads();

  // ---- phase 1b: build bf16 inputs from LDS fp32
  {
    if (tid < 192) {            // ego: 16 rows x 12 f32x4
      int row = tid / 12, c4 = tid % 12;
      f32x4 v = *reinterpret_cast<const f32x4*>(sObsF + row*168 + c4*4);
      bf16x4 bv = { (__bf16)v[0], (__bf16)v[1], (__bf16)v[2], (__bf16)v[3] };
      int off = (row*128 + c4*8) ^ ((row&7)<<4);
      *reinterpret_cast<bf16x4*>(reinterpret_cast<char*>(sEgoIn) + off) = bv;
    } else if (tid < 256) {     // ego zero pad cols 48..63
      int t = tid - 192;
      int row = t >> 2, ch = t & 3;
      bf16x4 z = {};
      int off = (row*128 + 96 + ch*8) ^ ((row&7)<<4);
      *reinterpret_cast<bf16x4*>(reinterpret_cast<char*>(sEgoIn) + off) = z;
    }
    if (tid >= 256 && tid < 496) {  // ado gather: 80 lds rows x 3 chunks of 8
      int t = tid - 256;
      int ldsrow = t / 3, p = t % 3;
      int n = ldsrow >> 4, r = ldsrow & 15;
      const float* orow = sObsF + r*168 + 48;
      bf16x8 v;
      #pragma unroll
      for (int j = 0; j < 8; ++j) v[j] = (__bf16)orow[(p*8+j)*5 + n];
      int off = (ldsrow*64 + p*16) ^ ((ldsrow&7)<<4);
      *reinterpret_cast<bf16x8*>(reinterpret_cast<char*>(sAdoIn) + off) = v;
    }
    if (tid >= 432) {               // cols 24..31: teamid + zero pad
      int t = tid - 432;            // 0..79
      int n = t >> 4;
      bf16x8 v = {};
      v[0] = (__bf16)((n >= 2) ? 1.0f : 0.0f);   // team_ids[1:6] = 0,0,1,1,1
      int off = (t*64 + 48) ^ ((t&7)<<4);
      *reinterpret_cast<bf16x8*>(reinterpret_cast<char*>(sAdoIn) + off) = v;
    }
  }
  __syncthreads();

  // ---- phase 2: ego0 + ado0 (agents 0..2 -> sH1 rows 0..47)
  gemm_block<64, 1, true>(sEgoIn, 0, sEgoH1, 0, ws + OFF_EGO0, eb0, w, lr, lg);
  gemm_block<32, 3, true>(sAdoIn, 0, sH1,    0, ws + OFF_ADO0, ab0, w, lr, lg);
  __syncthreads();

  // ---- phase 3: ego1
  gemm_block<256, 1, true>(sEgoH1, 0, sEgoH2, 0, ws + OFF_EGO1, eb1, w, lr, lg);
  __syncthreads();

  // ---- phase 4: sel (regs, 1/8 folded) + ado1 agents 0..2 -> sAdo2 rows 0..47
  f32x4 slct[2];
  {
    const __bf16* WT = ws + OFF_SEL;
    slct[0] = f32x4{0.f,0.f,0.f,0.f};
    slct[1] = f32x4{0.f,0.f,0.f,0.f};
    #pragma unroll
    for (int kb = 0; kb < 8; ++kb) {
      bf16x8 af = lds_loadA(sEgoH2, lr, kb*64 + lg*16, 512);
      #pragma unroll
      for (int c2 = 0; c2 < 2; ++c2) {
        bf16x8 bfr = *reinterpret_cast<const bf16x8*>(WT + (w*32+c2*16+lr)*256 + kb*32 + lg*8);
        slct[c2] = __builtin_amdgcn_mfma_f32_16x16x32_bf16(af, bfr, slct[c2], 0, 0, 0);
      }
    }
    slct[0] *= 0.125f;   // fold 1/sqrt(AD) into slct
    slct[1] *= 0.125f;
  }
  gemm_block<256, 3, true>(sH1, 0, sAdo2, 0, ws + OFF_ADO1, ab1, w, lr, lg);
  __syncthreads();

  // ---- phase 5: ado0 agents 3..4 -> sH1 rows 0..31
  gemm_block<32, 2, true>(sAdoIn, 48, sH1, 0, ws + OFF_ADO0, ab0, w, lr, lg);
  __syncthreads();

  // ---- phase 6: ado1 agents 3..4 -> sAdo2 rows 48..79
  gemm_block<256, 2, true>(sH1, 0, sAdo2, 48, ws + OFF_ADO1, ab1, w, lr, lg);
  __syncthreads();

  // ---- phase 7a: key pass, agent-grouped (3+2) to stay under the 64-VGPR
  // VALU envelope (kacc[3]+af[3] = 24 live vs 40).
  f32x4 part[5];
  #pragma unroll
  for (int n = 0; n < 5; ++n) part[n] = f32x4{0.f,0.f,0.f,0.f};
  {
    const __bf16* WK = ws + OFF_KEY;
    #pragma unroll
    for (int c2 = 0; c2 < 2; ++c2) {
      const int col = w*32 + c2*16 + lr;
      {
        f32x4 kacc[3];
        attn_pass<3>(sAdo2, WK, 0, col, lr, lg, kacc);
        #pragma unroll
        for (int n = 0; n < 3; ++n) part[n] += kacc[n] * slct[c2];
      }
      {
        f32x4 kacc[2];
        attn_pass<2>(sAdo2, WK, 3, col, lr, lg, kacc);
        #pragma unroll
        for (int n = 0; n < 2; ++n) part[3+n] += kacc[n] * slct[c2];
      }
    }
  }
  // reduce over lr lanes (sum over this wave's 32 d-dims)
  #pragma unroll
  for (int n = 0; n < 5; ++n) {
    #pragma unroll
    for (int m = 1; m < 16; m <<= 1) {
      part[n][0] += __shfl_xor(part[n][0], m);
      part[n][1] += __shfl_xor(part[n][1], m);
      part[n][2] += __shfl_xor(part[n][2], m);
      part[n][3] += __shfl_xor(part[n][3], m);
    }
  }
  // publish wave partials: sLogF[w][n][row] (f32x4 per (w,n,lg))
  #pragma unroll
  for (int n = 0; n < 5; ++n)
    if (lr == n)
      *reinterpret_cast<f32x4*>(sLogF + (w*5 + n)*16 + lg*4) = part[n];
  __syncthreads();
  // full logits = own + partner partial; exact softmax IN-PLACE in part[]
  {
    #pragma unroll
    for (int n = 0; n < 5; ++n)
      part[n] = *reinterpret_cast<const f32x4*>(sLogF + (w*5 + n)*16 + lg*4)
              + *reinterpret_cast<const f32x4*>(sLogF + ((w^1)*5 + n)*16 + lg*4);
    f32x4 mx = part[0];
    #pragma unroll
    for (int n = 1; n < 5; ++n)
      #pragma unroll
      for (int e = 0; e < 4; ++e) mx[e] = fmaxf(mx[e], part[n][e]);
    f32x4 s = f32x4{0.f,0.f,0.f,0.f};
    #pragma unroll
    for (int n = 0; n < 5; ++n) {
      #pragma unroll
      for (int e = 0; e < 4; ++e) part[n][e] = __expf(part[n][e] - mx[e]);
      s += part[n];
    }
    f32x4 inv;
    #pragma unroll
    for (int e = 0; e < 4; ++e) inv[e] = 1.0f / s[e];
    #pragma unroll
    for (int n = 0; n < 5; ++n) part[n] *= inv;
  }

  // ---- phase 7b: lat pass, same agent grouping; agg in regs
  f32x4 agg[2];
  agg[0] = f32x4{0.f,0.f,0.f,0.f};
  agg[1] = f32x4{0.f,0.f,0.f,0.f};
  {
    const __bf16* WL = ws + OFF_LAT;
    #pragma unroll
    for (int c2 = 0; c2 < 2; ++c2) {
      const int col = w*32 + c2*16 + lr;
      const float lb = latb[col];
      {
        f32x4 lacc[3];
        attn_pass<3>(sAdo2, WL, 0, col, lr, lg, lacc);
        #pragma unroll
        for (int n = 0; n < 3; ++n)
          #pragma unroll
          for (int e = 0; e < 4; ++e) {
            float x = lacc[n][e] + lb;
            x = x > 0.f ? x : 0.01f * x;
            agg[c2][e] += part[n][e] * x;
          }
      }
      {
        f32x4 lacc[2];
        attn_pass<2>(sAdo2, WL, 3, col, lr, lg, lacc);
        #pragma unroll
        for (int n = 0; n < 2; ++n)
          #pragma unroll
          for (int e = 0; e < 4; ++e) {
            float x = lacc[n][e] + lb;
            x = x > 0.f ? x : 0.01f * x;
            agg[c2][e] += part[3+n][e] * x;
          }
      }
    }
  }
  // agg -> sProj (proj input, bf16 swz). Overwrites sEgoH2 (dead).
  #pragma unroll
  for (int c2 = 0; c2 < 2; ++c2)
    #pragma unroll
    for (int e = 0; e < 4; ++e)
      lds_store_bf16(sProj, lg*4 + e, w*32 + c2*16 + lr, (__bf16)agg[c2][e]);
  __syncthreads();

  // ---- phase 8: proj (16x256)@(256x64); waves 0..3 -> cols w*16..w*16+15
  if (w < 4) {
    const __bf16* WT = ws + OFF_PROJ;
    f32x4 pacc = f32x4{0.f,0.f,0.f,0.f};
    #pragma unroll
    for (int kb = 0; kb < 8; ++kb) {
      bf16x8 af = lds_loadA(sProj, lr, kb*64 + lg*16, 512);
      bf16x8 bfr = *reinterpret_cast<const bf16x8*>(WT + (w*16+lr)*256 + kb*32 + lg*8);
      pacc = __builtin_amdgcn_mfma_f32_16x16x32_bf16(af, bfr, pacc, 0, 0, 0);
    }
    const float pb = projb[w*16 + lr];
    #pragma unroll
    for (int e = 0; e < 4; ++e)
      sOutF[(lg*4 + e)*64 + w*16 + lr] = pacc[e] + pb;
  }
  __syncthreads();

  // ---- phase 9: coalesced NT float4 writes of out[:, 48:112]
  if (tid < 256) {
    int row = tid >> 4, q = tid & 15;
    f32x4 v = *reinterpret_cast<const f32x4*>(sOutF + row*64 + q*4);
    __builtin_nontemporal_store(v,
        reinterpret_cast<f32x4*>(out + (size_t)(b0+row)*112 + 48 + q*4));
  }
}

extern "C" void kernel_launch(void* const* d_in, const int* in_sizes, int n_in,
                              void* d_out, int out_size, void* d_ws, size_t ws_size,
                              hipStream_t stream) {
  const float* obs   = (const float*)d_in[0];
  const float* ew0   = (const float*)d_in[1];
  const float* eb0   = (const float*)d_in[2];
  const float* ew1   = (const float*)d_in[3];
  const float* eb1   = (const float*)d_in[4];
  const float* aw0   = (const float*)d_in[5];
  const float* ab0   = (const float*)d_in[6];
  const float* aw1   = (const float*)d_in[7];
  const float* ab1   = (const float*)d_in[8];
  const float* keyw  = (const float*)d_in[9];
  const float* selw  = (const float*)d_in[10];
  const float* latw  = (const float*)d_in[11];
  const float* latb  = (const float*)d_in[12];
  const float* projw = (const float*)d_in[13];
  const float* projb = (const float*)d_in[14];
  __bf16* ws = (__bf16*)d_ws;
  float* out = (float*)d_out;

  prep_weights<<<dim3((WS_ELEMS + 255)/256), dim3(256), 0, stream>>>(
      ew0, ew1, aw0, aw1, keyw, selw, latw, projw, ws);
  fused_kernel<<<dim3(65536/16), dim3(512), 0, stream>>>(
      obs, eb0, eb1, ab0, ab1, latb, projb, ws, out);
}

// Round 11
// 498.405 us; speedup vs baseline: 1.0292x; 1.0292x over previous
//
#include <hip/hip_runtime.h>
#include <hip/hip_bf16.h>

// EncoderAttention4 v12: v6's chunked load batching + 256-reg budget (512,2).
// B=65536, NEGO=48, NADO=24, NADOAG=5, E=256, H=4, AD=64. Out: (B,112) fp32.
//
// Model (v2-v11 data): 512-thr kernels get 128 regs/wave (4 waves/SIMD of the
// 512-reg unified file); ~64 are AGPR accumulators -> 64-VGPR VALU ceiling.
// That ceiling is why VGPR_Count pinned at 64, why v6's load batching was
// re-serialized (no space for batch arrays), and why v5/v7/v11 spilled.
// Per-block time = ~76-150 SERIALIZED L2 B-fragment loads x 300-500cy.
// v2 (188 free regs, 1 block/CU) proves the compiler won't auto-pipeline;
// v3 (16 waves) proves TLP alone doesn't cure it. v12 tests the remaining
// combo: explicit chunked loads (v6) WITH registers to hold them:
// __launch_bounds__(512,2) -> 256 regs/wave, 8 waves/CU (1 resident block).
// Also keeps v10's NT obs loads.

typedef __bf16 bf16x8 __attribute__((ext_vector_type(8)));
typedef __bf16 bf16x4 __attribute__((ext_vector_type(4)));
typedef float  f32x4  __attribute__((ext_vector_type(4)));

// Workspace layout (bf16 elements), unchanged.
#define OFF_EGO0 0        // [256][64]  (K=48 padded to 64)
#define OFF_EGO1 16384    // [256][256]
#define OFF_ADO0 81920    // [256][32]  (K=25 padded to 32)
#define OFF_ADO1 90112    // [256][256]
#define OFF_SEL  155648   // [256][256] col c -> head c>>6, d c&63
#define OFF_KEY  221184
#define OFF_LAT  286720
#define OFF_PROJ 352256   // [64][256]
#define WS_ELEMS 368640

__global__ __launch_bounds__(256) void prep_weights(
    const float* __restrict__ ew0, const float* __restrict__ ew1,
    const float* __restrict__ aw0, const float* __restrict__ aw1,
    const float* __restrict__ keyw, const float* __restrict__ selw,
    const float* __restrict__ latw, const float* __restrict__ projw,
    __bf16* __restrict__ ws)
{
  int i = blockIdx.x * 256 + threadIdx.x;
  if (i >= WS_ELEMS) return;
  float v;
  if (i < OFF_EGO1)      { int j=i;          int c=j>>6, k=j&63;  v = (k<48) ? ew0[k*256+c] : 0.f; }
  else if (i < OFF_ADO0) { int j=i-OFF_EGO1; int c=j>>8, k=j&255; v = ew1[k*256+c]; }
  else if (i < OFF_ADO1) { int j=i-OFF_ADO0; int c=j>>5, k=j&31;  v = (k<25) ? aw0[k*256+c] : 0.f; }
  else if (i < OFF_SEL)  { int j=i-OFF_ADO1; int c=j>>8, k=j&255; v = aw1[k*256+c]; }
  else if (i < OFF_KEY)  { int j=i-OFF_SEL;  int c=j>>8, k=j&255; v = selw[(c>>6)*16384 + k*64 + (c&63)]; }
  else if (i < OFF_LAT)  { int j=i-OFF_KEY;  int c=j>>8, k=j&255; v = keyw[(c>>6)*16384 + k*64 + (c&63)]; }
  else if (i < OFF_PROJ) { int j=i-OFF_LAT;  int c=j>>8, k=j&255; v = latw[(c>>6)*16384 + k*64 + (c&63)]; }
  else                   { int j=i-OFF_PROJ; int c=j>>8, k=j&255; v = projw[k*64+c]; }
  ws[i] = (__bf16)v;
}

// XOR-swizzled LDS accessors. byte ^= (row&7)<<4.
__device__ __forceinline__ bf16x8 lds_loadA(const __bf16* base, int row, int kByte, int rowBytes) {
  int off = (row * rowBytes + kByte) ^ ((row & 7) << 4);
  return *reinterpret_cast<const bf16x8*>(reinterpret_cast<const char*>(base) + off);
}
__device__ __forceinline__ void lds_store_bf16(__bf16* base, int row, int col, __bf16 v) {
  int off = (row * 512 + col * 2) ^ ((row & 7) << 4);  // 256-col tiles only
  *reinterpret_cast<__bf16*>(reinterpret_cast<char*>(base) + off) = v;
}

// LDS pool (bytes). Aliased regions with phase-disjoint lifetimes (as v3).
#define P_ADO2   0
#define P_EGOIN  0
#define P_EGOH1  2048
#define P_ADOIN  24576
#define P_EGOH2  40960
#define P_PROJIN 40960
#define P_H1     49152
#define P_OBSRAW 49152
#define P_OUT    73728
#define POOL_BYTES 77824   // 76KB; occupancy now reg-limited to 1 block/CU

// C(out 16R rows x 32 cols/wave) = act(A @ WT^T + bias). Column-split:
// wave w owns cols w*32 + c2*16 + lr. B loaded once per block.
// CHUNKED: loads for C kb-steps are issued as a batch (register arrays)
// before the chunk's MFMAs -> 2*C outstanding vmem loads per wave.
template<int KP, int R, int C, bool ACT>
__device__ __forceinline__ void gemm_block(const __bf16* __restrict__ sA, int aRow0,
                                           __bf16* __restrict__ sC, int cRow0,
                                           const __bf16* __restrict__ WT,
                                           const float* __restrict__ bias,
                                           int w, int lr, int lg)
{
  constexpr int NKB = KP / 32;
  static_assert(NKB % C == 0, "chunk must divide NKB");
  f32x4 acc[R][2];
  #pragma unroll
  for (int t = 0; t < R; ++t) {
    acc[t][0] = f32x4{0.f,0.f,0.f,0.f};
    acc[t][1] = f32x4{0.f,0.f,0.f,0.f};
  }
  const int col0 = w*32 + lr;
  #pragma unroll
  for (int kc = 0; kc < NKB; kc += C) {
    // batch: issue all B loads first (longest latency), then A ds_reads
    bf16x8 bfr[C][2];
    #pragma unroll
    for (int j = 0; j < C; ++j)
      #pragma unroll
      for (int c2 = 0; c2 < 2; ++c2)
        bfr[j][c2] = *reinterpret_cast<const bf16x8*>(
            WT + (col0 + c2*16)*KP + (kc+j)*32 + lg*8);
    bf16x8 af[C][R];
    #pragma unroll
    for (int j = 0; j < C; ++j)
      #pragma unroll
      for (int t = 0; t < R; ++t)
        af[j][t] = lds_loadA(sA, aRow0 + t*16 + lr, (kc+j)*64 + lg*16, KP*2);
    #pragma unroll
    for (int j = 0; j < C; ++j)
      #pragma unroll
      for (int c2 = 0; c2 < 2; ++c2)
        #pragma unroll
        for (int t = 0; t < R; ++t)
          acc[t][c2] = __builtin_amdgcn_mfma_f32_16x16x32_bf16(af[j][t], bfr[j][c2], acc[t][c2], 0, 0, 0);
  }
  #pragma unroll
  for (int c2 = 0; c2 < 2; ++c2) {
    const int col = col0 + c2*16;
    const float bv = bias[col];
    #pragma unroll
    for (int t = 0; t < R; ++t) {
      #pragma unroll
      for (int e = 0; e < 4; ++e) {
        float x = acc[t][c2][e] + bv;
        if (ACT) x = x > 0.f ? x : 0.01f * x;
        lds_store_bf16(sC, cRow0 + t*16 + lg*4 + e, col, (__bf16)x);
      }
    }
  }
}

__global__ __launch_bounds__(512, 2) void fused_kernel(
    const float* __restrict__ obs,
    const float* __restrict__ eb0, const float* __restrict__ eb1,
    const float* __restrict__ ab0, const float* __restrict__ ab1,
    const float* __restrict__ latb, const float* __restrict__ projb,
    const __bf16* __restrict__ ws,
    float* __restrict__ out)
{
  const int tid = threadIdx.x;
  const int w  = tid >> 6;   // 8 waves
  const int l  = tid & 63;
  const int lr = l & 15;
  const int lg = l >> 4;
  const int b0 = blockIdx.x * 16;

  __shared__ __align__(16) char pool[POOL_BYTES];
  __bf16* sEgoIn = reinterpret_cast<__bf16*>(pool + P_EGOIN);
  __bf16* sEgoH1 = reinterpret_cast<__bf16*>(pool + P_EGOH1);
  __bf16* sAdoIn = reinterpret_cast<__bf16*>(pool + P_ADOIN);
  __bf16* sEgoH2 = reinterpret_cast<__bf16*>(pool + P_EGOH2);
  __bf16* sProj  = reinterpret_cast<__bf16*>(pool + P_PROJIN);
  __bf16* sAdo2  = reinterpret_cast<__bf16*>(pool + P_ADO2);
  __bf16* sH1    = reinterpret_cast<__bf16*>(pool + P_H1);
  float*  sObsF  = reinterpret_cast<float*>(pool + P_OBSRAW);
  float*  sLogF  = reinterpret_cast<float*>(pool + P_OUT);
  float*  sOutF  = reinterpret_cast<float*>(pool + P_OUT);

  // ---- phase 1a: NT coalesced obs -> LDS (fp32) + NT passthrough out[:, :48]
  {
    const f32x4* o4 = reinterpret_cast<const f32x4*>(obs);
    #pragma unroll
    for (int idx = tid; idx < 672; idx += 512) {   // 16 rows x 42 f32x4
      int row = idx / 42, c4 = idx % 42;
      f32x4 v = __builtin_nontemporal_load(o4 + (size_t)(b0+row)*42 + c4);
      *reinterpret_cast<f32x4*>(sObsF + row*168 + c4*4) = v;
      if (c4 < 12)
        __builtin_nontemporal_store(v,
            reinterpret_cast<f32x4*>(out + (size_t)(b0+row)*112 + c4*4));
    }
  }
  __syncthreads();

  // ---- phase 1b: build bf16 inputs from LDS fp32
  {
    if (tid < 192) {            // ego: 16 rows x 12 f32x4
      int row = tid / 12, c4 = tid % 12;
      f32x4 v = *reinterpret_cast<const f32x4*>(sObsF + row*168 + c4*4);
      bf16x4 bv = { (__bf16)v[0], (__bf16)v[1], (__bf16)v[2], (__bf16)v[3] };
      int off = (row*128 + c4*8) ^ ((row&7)<<4);
      *reinterpret_cast<bf16x4*>(reinterpret_cast<char*>(sEgoIn) + off) = bv;
    } else if (tid < 256) {     // ego zero pad cols 48..63
      int t = tid - 192;
      int row = t >> 2, ch = t & 3;
      bf16x4 z = {};
      int off = (row*128 + 96 + ch*8) ^ ((row&7)<<4);
      *reinterpret_cast<bf16x4*>(reinterpret_cast<char*>(sEgoIn) + off) = z;
    }
    if (tid >= 256 && tid < 496) {  // ado gather: 80 lds rows x 3 chunks of 8
      int t = tid - 256;
      int ldsrow = t / 3, p = t % 3;
      int n = ldsrow >> 4, r = ldsrow & 15;
      const float* orow = sObsF + r*168 + 48;
      bf16x8 v;
      #pragma unroll
      for (int j = 0; j < 8; ++j) v[j] = (__bf16)orow[(p*8+j)*5 + n];
      int off = (ldsrow*64 + p*16) ^ ((ldsrow&7)<<4);
      *reinterpret_cast<bf16x8*>(reinterpret_cast<char*>(sAdoIn) + off) = v;
    }
    if (tid >= 432) {               // cols 24..31: teamid + zero pad
      int t = tid - 432;            // 0..79
      int n = t >> 4;
      bf16x8 v = {};
      v[0] = (__bf16)((n >= 2) ? 1.0f : 0.0f);   // team_ids[1:6] = 0,0,1,1,1
      int off = (t*64 + 48) ^ ((t&7)<<4);
      *reinterpret_cast<bf16x8*>(reinterpret_cast<char*>(sAdoIn) + off) = v;
    }
  }
  __syncthreads();

  // ---- phase 2: ego0 + ado0 (agents 0..2 -> sH1 rows 0..47)
  gemm_block<64, 1, 2, true>(sEgoIn, 0, sEgoH1, 0, ws + OFF_EGO0, eb0, w, lr, lg);
  gemm_block<32, 3, 1, true>(sAdoIn, 0, sH1,    0, ws + OFF_ADO0, ab0, w, lr, lg);
  __syncthreads();

  // ---- phase 3: ego1 (C=8: 16 B loads batched in regs)
  gemm_block<256, 1, 8, true>(sEgoH1, 0, sEgoH2, 0, ws + OFF_EGO1, eb1, w, lr, lg);
  __syncthreads();

  // ---- phase 4: sel (regs, 1/8 folded, C=4 batching) + ado1 agents 0..2
  f32x4 slct[2];
  {
    const __bf16* WT = ws + OFF_SEL;
    slct[0] = f32x4{0.f,0.f,0.f,0.f};
    slct[1] = f32x4{0.f,0.f,0.f,0.f};
    #pragma unroll
    for (int kc = 0; kc < 8; kc += 4) {
      bf16x8 bfr[4][2];
      #pragma unroll
      for (int j = 0; j < 4; ++j)
        #pragma unroll
        for (int c2 = 0; c2 < 2; ++c2)
          bfr[j][c2] = *reinterpret_cast<const bf16x8*>(
              WT + (w*32 + c2*16 + lr)*256 + (kc+j)*32 + lg*8);
      bf16x8 af[4];
      #pragma unroll
      for (int j = 0; j < 4; ++j)
        af[j] = lds_loadA(sEgoH2, lr, (kc+j)*64 + lg*16, 512);
      #pragma unroll
      for (int j = 0; j < 4; ++j)
        #pragma unroll
        for (int c2 = 0; c2 < 2; ++c2)
          slct[c2] = __builtin_amdgcn_mfma_f32_16x16x32_bf16(af[j], bfr[j][c2], slct[c2], 0, 0, 0);
    }
    slct[0] *= 0.125f;   // fold 1/sqrt(AD) into slct
    slct[1] *= 0.125f;
  }
  gemm_block<256, 3, 4, true>(sH1, 0, sAdo2, 0, ws + OFF_ADO1, ab1, w, lr, lg);
  __syncthreads();

  // ---- phase 5: ado0 agents 3..4 -> sH1 rows 0..31
  gemm_block<32, 2, 1, true>(sAdoIn, 48, sH1, 0, ws + OFF_ADO0, ab0, w, lr, lg);
  __syncthreads();

  // ---- phase 6: ado1 agents 3..4 -> sAdo2 rows 48..79
  gemm_block<256, 2, 4, true>(sH1, 0, sAdo2, 48, ws + OFF_ADO1, ab1, w, lr, lg);
  __syncthreads();

  // ---- phase 7a: key pass, chunked C=2 (bk[2][2] + af[2][5] batched)
  f32x4 part[5];
  {
    const __bf16* WK = ws + OFF_KEY;
    f32x4 kacc[5][2];
    #pragma unroll
    for (int n = 0; n < 5; ++n) {
      kacc[n][0] = f32x4{0.f,0.f,0.f,0.f};
      kacc[n][1] = f32x4{0.f,0.f,0.f,0.f};
    }
    #pragma unroll
    for (int kc = 0; kc < 8; kc += 2) {
      bf16x8 bk[2][2];
      #pragma unroll
      for (int j = 0; j < 2; ++j)
        #pragma unroll
        for (int c2 = 0; c2 < 2; ++c2)
          bk[j][c2] = *reinterpret_cast<const bf16x8*>(
              WK + (w*32 + c2*16 + lr)*256 + (kc+j)*32 + lg*8);
      bf16x8 af[2][5];
      #pragma unroll
      for (int j = 0; j < 2; ++j)
        #pragma unroll
        for (int n = 0; n < 5; ++n)
          af[j][n] = lds_loadA(sAdo2, n*16 + lr, (kc+j)*64 + lg*16, 512);
      #pragma unroll
      for (int j = 0; j < 2; ++j)
        #pragma unroll
        for (int c2 = 0; c2 < 2; ++c2)
          #pragma unroll
          for (int n = 0; n < 5; ++n)
            kacc[n][c2] = __builtin_amdgcn_mfma_f32_16x16x32_bf16(af[j][n], bk[j][c2], kacc[n][c2], 0, 0, 0);
    }
    #pragma unroll
    for (int n = 0; n < 5; ++n)
      part[n] = kacc[n][0]*slct[0] + kacc[n][1]*slct[1];
  }
  // reduce over lr lanes (sum over this wave's 32 d-dims)
  #pragma unroll
  for (int n = 0; n < 5; ++n) {
    #pragma unroll
    for (int m = 1; m < 16; m <<= 1) {
      part[n][0] += __shfl_xor(part[n][0], m);
      part[n][1] += __shfl_xor(part[n][1], m);
      part[n][2] += __shfl_xor(part[n][2], m);
      part[n][3] += __shfl_xor(part[n][3], m);
    }
  }
  // publish wave partials: sLogF[w][n][row] (f32x4 per (w,n,lg))
  #pragma unroll
  for (int n = 0; n < 5; ++n)
    if (lr == n)
      *reinterpret_cast<f32x4*>(sLogF + (w*5 + n)*16 + lg*4) = part[n];
  __syncthreads();
  // full logits = own + partner partial; exact softmax in-place in part[]
  {
    #pragma unroll
    for (int n = 0; n < 5; ++n)
      part[n] = *reinterpret_cast<const f32x4*>(sLogF + (w*5 + n)*16 + lg*4)
              + *reinterpret_cast<const f32x4*>(sLogF + ((w^1)*5 + n)*16 + lg*4);
    f32x4 mx = part[0];
    #pragma unroll
    for (int n = 1; n < 5; ++n)
      #pragma unroll
      for (int e = 0; e < 4; ++e) mx[e] = fmaxf(mx[e], part[n][e]);
    f32x4 s = f32x4{0.f,0.f,0.f,0.f};
    #pragma unroll
    for (int n = 0; n < 5; ++n) {
      #pragma unroll
      for (int e = 0; e < 4; ++e) part[n][e] = __expf(part[n][e] - mx[e]);
      s += part[n];
    }
    f32x4 inv;
    #pragma unroll
    for (int e = 0; e < 4; ++e) inv[e] = 1.0f / s[e];
    #pragma unroll
    for (int n = 0; n < 5; ++n) part[n] *= inv;
  }

  // ---- phase 7b: lat pass, same chunked shape; agg in regs
  f32x4 agg[2];
  agg[0] = f32x4{0.f,0.f,0.f,0.f};
  agg[1] = f32x4{0.f,0.f,0.f,0.f};
  {
    const __bf16* WL = ws + OFF_LAT;
    f32x4 lacc[5][2];
    #pragma unroll
    for (int n = 0; n < 5; ++n) {
      lacc[n][0] = f32x4{0.f,0.f,0.f,0.f};
      lacc[n][1] = f32x4{0.f,0.f,0.f,0.f};
    }
    #pragma unroll
    for (int kc = 0; kc < 8; kc += 2) {
      bf16x8 bl[2][2];
      #pragma unroll
      for (int j = 0; j < 2; ++j)
        #pragma unroll
        for (int c2 = 0; c2 < 2; ++c2)
          bl[j][c2] = *reinterpret_cast<const bf16x8*>(
              WL + (w*32 + c2*16 + lr)*256 + (kc+j)*32 + lg*8);
      bf16x8 af[2][5];
      #pragma unroll
      for (int j = 0; j < 2; ++j)
        #pragma unroll
        for (int n = 0; n < 5; ++n)
          af[j][n] = lds_loadA(sAdo2, n*16 + lr, (kc+j)*64 + lg*16, 512);
      #pragma unroll
      for (int j = 0; j < 2; ++j)
        #pragma unroll
        for (int c2 = 0; c2 < 2; ++c2)
          #pragma unroll
          for (int n = 0; n < 5; ++n)
            lacc[n][c2] = __builtin_amdgcn_mfma_f32_16x16x32_bf16(af[j][n], bl[j][c2], lacc[n][c2], 0, 0, 0);
    }
    #pragma unroll
    for (int c2 = 0; c2 < 2; ++c2) {
      const float lb = latb[w*32 + c2*16 + lr];
      #pragma unroll
      for (int n = 0; n < 5; ++n) {
        #pragma unroll
        for (int e = 0; e < 4; ++e) {
          float x = lacc[n][c2][e] + lb;
          x = x > 0.f ? x : 0.01f * x;
          agg[c2][e] += part[n][e] * x;
        }
      }
    }
  }
  // agg -> sProj (proj input, bf16 swz). Overwrites sEgoH2 (dead).
  #pragma unroll
  for (int c2 = 0; c2 < 2; ++c2)
    #pragma unroll
    for (int e = 0; e < 4; ++e)
      lds_store_bf16(sProj, lg*4 + e, w*32 + c2*16 + lr, (__bf16)agg[c2][e]);
  __syncthreads();

  // ---- phase 8: proj (16x256)@(256x64); waves 0..3 -> cols w*16..w*16+15
  if (w < 4) {
    const __bf16* WT = ws + OFF_PROJ;
    f32x4 pacc = f32x4{0.f,0.f,0.f,0.f};
    #pragma unroll
    for (int kc = 0; kc < 8; kc += 4) {
      bf16x8 bfr[4];
      #pragma unroll
      for (int j = 0; j < 4; ++j)
        bfr[j] = *reinterpret_cast<const bf16x8*>(WT + (w*16+lr)*256 + (kc+j)*32 + lg*8);
      bf16x8 af[4];
      #pragma unroll
      for (int j = 0; j < 4; ++j)
        af[j] = lds_loadA(sProj, lr, (kc+j)*64 + lg*16, 512);
      #pragma unroll
      for (int j = 0; j < 4; ++j)
        pacc = __builtin_amdgcn_mfma_f32_16x16x32_bf16(af[j], bfr[j], pacc, 0, 0, 0);
    }
    const float pb = projb[w*16 + lr];
    #pragma unroll
    for (int e = 0; e < 4; ++e)
      sOutF[(lg*4 + e)*64 + w*16 + lr] = pacc[e] + pb;
  }
  __syncthreads();

  // ---- phase 9: coalesced NT float4 writes of out[:, 48:112]
  if (tid < 256) {
    int row = tid >> 4, q = tid & 15;
    f32x4 v = *reinterpret_cast<const f32x4*>(sOutF + row*64 + q*4);
    __builtin_nontemporal_store(v,
        reinterpret_cast<f32x4*>(out + (size_t)(b0+row)*112 + 48 + q*4));
  }
}

extern "C" void kernel_launch(void* const* d_in, const int* in_sizes, int n_in,
                              void* d_out, int out_size, void* d_ws, size_t ws_size,
                              hipStream_t stream) {
  const float* obs   = (const float*)d_in[0];
  const float* ew0   = (const float*)d_in[1];
  const float* eb0   = (const float*)d_in[2];
  const float* ew1   = (const float*)d_in[3];
  const float* eb1   = (const float*)d_in[4];
  const float* aw0   = (const float*)d_in[5];
  const float* ab0   = (const float*)d_in[6];
  const float* aw1   = (const float*)d_in[7];
  const float* ab1   = (const float*)d_in[8];
  const float* keyw  = (const float*)d_in[9];
  const float* selw  = (const float*)d_in[10];
  const float* latw  = (const float*)d_in[11];
  const float* latb  = (const float*)d_in[12];
  const float* projw = (const float*)d_in[13];
  const float* projb = (const float*)d_in[14];
  __bf16* ws = (__bf16*)d_ws;
  float* out = (float*)d_out;

  prep_weights<<<dim3((WS_ELEMS + 255)/256), dim3(256), 0, stream>>>(
      ew0, ew1, aw0, aw1, keyw, selw, latw, projw, ws);
  fused_kernel<<<dim3(65536/16), dim3(512), 0, stream>>>(
      obs, eb0, eb1, ab0, ab1, latb, projb, ws, out);
}

// Round 12
// 470.890 us; speedup vs baseline: 1.0893x; 1.0584x over previous
//
#include <hip/hip_runtime.h>
#include <hip/hip_bf16.h>

// EncoderAttention4 v13: v12's register-held load batching trimmed to fit a
// 128-reg/wave total -> 2 blocks/CU (16 waves) WITH batching.
// B=65536, NEGO=48, NADO=24, NADOAG=5, E=256, H=4, AD=64. Out: (B,112) fp32.
//
// v12 post-mortem: batching + 256-reg budget worked (VGPR 88, traffic ideal
// 31MB/24MB, per-wave efficiency 1.8x v3) but 1 block/CU halved waves ->
// 498us. v6 failed the same idea at (512,4) because its demand (~150) blew
// the 128 budget (re-serialize + spill). v13 trims peak demand to ~110:
//  - phase 7 c2-OUTER (kacc[5]=20 AGPR, not kacc[5][2]=40), C=2 af/bk
//    batches kept inside each c2 half
//  - ego1 chunk C=4 (was 8), ado1 pieces C=2 (was 4)
// Tells: VGPR ~84-96 AND occupancy ~46% AND WRITE ~31MB => dur 340-410.
// If VGPR pins to 64, this axis is dead (next: 32-row deep-block @ 256 regs).

typedef __bf16 bf16x8 __attribute__((ext_vector_type(8)));
typedef __bf16 bf16x4 __attribute__((ext_vector_type(4)));
typedef float  f32x4  __attribute__((ext_vector_type(4)));

// Workspace layout (bf16 elements), unchanged.
#define OFF_EGO0 0        // [256][64]  (K=48 padded to 64)
#define OFF_EGO1 16384    // [256][256]
#define OFF_ADO0 81920    // [256][32]  (K=25 padded to 32)
#define OFF_ADO1 90112    // [256][256]
#define OFF_SEL  155648   // [256][256] col c -> head c>>6, d c&63
#define OFF_KEY  221184
#define OFF_LAT  286720
#define OFF_PROJ 352256   // [64][256]
#define WS_ELEMS 368640

__global__ __launch_bounds__(256) void prep_weights(
    const float* __restrict__ ew0, const float* __restrict__ ew1,
    const float* __restrict__ aw0, const float* __restrict__ aw1,
    const float* __restrict__ keyw, const float* __restrict__ selw,
    const float* __restrict__ latw, const float* __restrict__ projw,
    __bf16* __restrict__ ws)
{
  int i = blockIdx.x * 256 + threadIdx.x;
  if (i >= WS_ELEMS) return;
  float v;
  if (i < OFF_EGO1)      { int j=i;          int c=j>>6, k=j&63;  v = (k<48) ? ew0[k*256+c] : 0.f; }
  else if (i < OFF_ADO0) { int j=i-OFF_EGO1; int c=j>>8, k=j&255; v = ew1[k*256+c]; }
  else if (i < OFF_ADO1) { int j=i-OFF_ADO0; int c=j>>5, k=j&31;  v = (k<25) ? aw0[k*256+c] : 0.f; }
  else if (i < OFF_SEL)  { int j=i-OFF_ADO1; int c=j>>8, k=j&255; v = aw1[k*256+c]; }
  else if (i < OFF_KEY)  { int j=i-OFF_SEL;  int c=j>>8, k=j&255; v = selw[(c>>6)*16384 + k*64 + (c&63)]; }
  else if (i < OFF_LAT)  { int j=i-OFF_KEY;  int c=j>>8, k=j&255; v = keyw[(c>>6)*16384 + k*64 + (c&63)]; }
  else if (i < OFF_PROJ) { int j=i-OFF_LAT;  int c=j>>8, k=j&255; v = latw[(c>>6)*16384 + k*64 + (c&63)]; }
  else                   { int j=i-OFF_PROJ; int c=j>>8, k=j&255; v = projw[k*64+c]; }
  ws[i] = (__bf16)v;
}

// XOR-swizzled LDS accessors. byte ^= (row&7)<<4.
__device__ __forceinline__ bf16x8 lds_loadA(const __bf16* base, int row, int kByte, int rowBytes) {
  int off = (row * rowBytes + kByte) ^ ((row & 7) << 4);
  return *reinterpret_cast<const bf16x8*>(reinterpret_cast<const char*>(base) + off);
}
__device__ __forceinline__ void lds_store_bf16(__bf16* base, int row, int col, __bf16 v) {
  int off = (row * 512 + col * 2) ^ ((row & 7) << 4);  // 256-col tiles only
  *reinterpret_cast<__bf16*>(reinterpret_cast<char*>(base) + off) = v;
}

// LDS pool (bytes). Aliased regions with phase-disjoint lifetimes (as v3).
#define P_ADO2   0
#define P_EGOIN  0
#define P_EGOH1  2048
#define P_ADOIN  24576
#define P_EGOH2  40960
#define P_PROJIN 40960
#define P_H1     49152
#define P_OBSRAW 49152
#define P_OUT    73728
#define POOL_BYTES 77824   // 76KB -> 2 blocks/CU if regs <= 128/wave

// C(out 16R rows x 32 cols/wave) = act(A @ WT^T + bias). Column-split:
// wave w owns cols w*32 + c2*16 + lr. B loaded once per block.
// CHUNKED: loads for C kb-steps batched in register arrays before the MFMAs.
template<int KP, int R, int C, bool ACT>
__device__ __forceinline__ void gemm_block(const __bf16* __restrict__ sA, int aRow0,
                                           __bf16* __restrict__ sC, int cRow0,
                                           const __bf16* __restrict__ WT,
                                           const float* __restrict__ bias,
                                           int w, int lr, int lg)
{
  constexpr int NKB = KP / 32;
  static_assert(NKB % C == 0, "chunk must divide NKB");
  f32x4 acc[R][2];
  #pragma unroll
  for (int t = 0; t < R; ++t) {
    acc[t][0] = f32x4{0.f,0.f,0.f,0.f};
    acc[t][1] = f32x4{0.f,0.f,0.f,0.f};
  }
  const int col0 = w*32 + lr;
  #pragma unroll
  for (int kc = 0; kc < NKB; kc += C) {
    bf16x8 bfr[C][2];
    #pragma unroll
    for (int j = 0; j < C; ++j)
      #pragma unroll
      for (int c2 = 0; c2 < 2; ++c2)
        bfr[j][c2] = *reinterpret_cast<const bf16x8*>(
            WT + (col0 + c2*16)*KP + (kc+j)*32 + lg*8);
    bf16x8 af[C][R];
    #pragma unroll
    for (int j = 0; j < C; ++j)
      #pragma unroll
      for (int t = 0; t < R; ++t)
        af[j][t] = lds_loadA(sA, aRow0 + t*16 + lr, (kc+j)*64 + lg*16, KP*2);
    #pragma unroll
    for (int j = 0; j < C; ++j)
      #pragma unroll
      for (int c2 = 0; c2 < 2; ++c2)
        #pragma unroll
        for (int t = 0; t < R; ++t)
          acc[t][c2] = __builtin_amdgcn_mfma_f32_16x16x32_bf16(af[j][t], bfr[j][c2], acc[t][c2], 0, 0, 0);
  }
  #pragma unroll
  for (int c2 = 0; c2 < 2; ++c2) {
    const int col = col0 + c2*16;
    const float bv = bias[col];
    #pragma unroll
    for (int t = 0; t < R; ++t) {
      #pragma unroll
      for (int e = 0; e < 4; ++e) {
        float x = acc[t][c2][e] + bv;
        if (ACT) x = x > 0.f ? x : 0.01f * x;
        lds_store_bf16(sC, cRow0 + t*16 + lg*4 + e, col, (__bf16)x);
      }
    }
  }
}

__global__ __launch_bounds__(512, 4) void fused_kernel(
    const float* __restrict__ obs,
    const float* __restrict__ eb0, const float* __restrict__ eb1,
    const float* __restrict__ ab0, const float* __restrict__ ab1,
    const float* __restrict__ latb, const float* __restrict__ projb,
    const __bf16* __restrict__ ws,
    float* __restrict__ out)
{
  const int tid = threadIdx.x;
  const int w  = tid >> 6;   // 8 waves
  const int l  = tid & 63;
  const int lr = l & 15;
  const int lg = l >> 4;
  const int b0 = blockIdx.x * 16;

  __shared__ __align__(16) char pool[POOL_BYTES];
  __bf16* sEgoIn = reinterpret_cast<__bf16*>(pool + P_EGOIN);
  __bf16* sEgoH1 = reinterpret_cast<__bf16*>(pool + P_EGOH1);
  __bf16* sAdoIn = reinterpret_cast<__bf16*>(pool + P_ADOIN);
  __bf16* sEgoH2 = reinterpret_cast<__bf16*>(pool + P_EGOH2);
  __bf16* sProj  = reinterpret_cast<__bf16*>(pool + P_PROJIN);
  __bf16* sAdo2  = reinterpret_cast<__bf16*>(pool + P_ADO2);
  __bf16* sH1    = reinterpret_cast<__bf16*>(pool + P_H1);
  float*  sObsF  = reinterpret_cast<float*>(pool + P_OBSRAW);
  float*  sLogF  = reinterpret_cast<float*>(pool + P_OUT);
  float*  sOutF  = reinterpret_cast<float*>(pool + P_OUT);

  // ---- phase 1a: NT coalesced obs -> LDS (fp32) + NT passthrough out[:, :48]
  {
    const f32x4* o4 = reinterpret_cast<const f32x4*>(obs);
    #pragma unroll
    for (int idx = tid; idx < 672; idx += 512) {   // 16 rows x 42 f32x4
      int row = idx / 42, c4 = idx % 42;
      f32x4 v = __builtin_nontemporal_load(o4 + (size_t)(b0+row)*42 + c4);
      *reinterpret_cast<f32x4*>(sObsF + row*168 + c4*4) = v;
      if (c4 < 12)
        __builtin_nontemporal_store(v,
            reinterpret_cast<f32x4*>(out + (size_t)(b0+row)*112 + c4*4));
    }
  }
  __syncthreads();

  // ---- phase 1b: build bf16 inputs from LDS fp32
  {
    if (tid < 192) {            // ego: 16 rows x 12 f32x4
      int row = tid / 12, c4 = tid % 12;
      f32x4 v = *reinterpret_cast<const f32x4*>(sObsF + row*168 + c4*4);
      bf16x4 bv = { (__bf16)v[0], (__bf16)v[1], (__bf16)v[2], (__bf16)v[3] };
      int off = (row*128 + c4*8) ^ ((row&7)<<4);
      *reinterpret_cast<bf16x4*>(reinterpret_cast<char*>(sEgoIn) + off) = bv;
    } else if (tid < 256) {     // ego zero pad cols 48..63
      int t = tid - 192;
      int row = t >> 2, ch = t & 3;
      bf16x4 z = {};
      int off = (row*128 + 96 + ch*8) ^ ((row&7)<<4);
      *reinterpret_cast<bf16x4*>(reinterpret_cast<char*>(sEgoIn) + off) = z;
    }
    if (tid >= 256 && tid < 496) {  // ado gather: 80 lds rows x 3 chunks of 8
      int t = tid - 256;
      int ldsrow = t / 3, p = t % 3;
      int n = ldsrow >> 4, r = ldsrow & 15;
      const float* orow = sObsF + r*168 + 48;
      bf16x8 v;
      #pragma unroll
      for (int j = 0; j < 8; ++j) v[j] = (__bf16)orow[(p*8+j)*5 + n];
      int off = (ldsrow*64 + p*16) ^ ((ldsrow&7)<<4);
      *reinterpret_cast<bf16x8*>(reinterpret_cast<char*>(sAdoIn) + off) = v;
    }
    if (tid >= 432) {               // cols 24..31: teamid + zero pad
      int t = tid - 432;            // 0..79
      int n = t >> 4;
      bf16x8 v = {};
      v[0] = (__bf16)((n >= 2) ? 1.0f : 0.0f);   // team_ids[1:6] = 0,0,1,1,1
      int off = (t*64 + 48) ^ ((t&7)<<4);
      *reinterpret_cast<bf16x8*>(reinterpret_cast<char*>(sAdoIn) + off) = v;
    }
  }
  __syncthreads();

  // ---- phase 2: ego0 + ado0 (agents 0..2 -> sH1 rows 0..47)
  gemm_block<64, 1, 2, true>(sEgoIn, 0, sEgoH1, 0, ws + OFF_EGO0, eb0, w, lr, lg);
  gemm_block<32, 3, 1, true>(sAdoIn, 0, sH1,    0, ws + OFF_ADO0, ab0, w, lr, lg);
  __syncthreads();

  // ---- phase 3: ego1 (C=4 batching)
  gemm_block<256, 1, 4, true>(sEgoH1, 0, sEgoH2, 0, ws + OFF_EGO1, eb1, w, lr, lg);
  __syncthreads();

  // ---- phase 4: sel (regs, 1/8 folded, C=4 batching) + ado1 agents 0..2 (C=2)
  f32x4 slct[2];
  {
    const __bf16* WT = ws + OFF_SEL;
    slct[0] = f32x4{0.f,0.f,0.f,0.f};
    slct[1] = f32x4{0.f,0.f,0.f,0.f};
    #pragma unroll
    for (int kc = 0; kc < 8; kc += 4) {
      bf16x8 bfr[4][2];
      #pragma unroll
      for (int j = 0; j < 4; ++j)
        #pragma unroll
        for (int c2 = 0; c2 < 2; ++c2)
          bfr[j][c2] = *reinterpret_cast<const bf16x8*>(
              WT + (w*32 + c2*16 + lr)*256 + (kc+j)*32 + lg*8);
      bf16x8 af[4];
      #pragma unroll
      for (int j = 0; j < 4; ++j)
        af[j] = lds_loadA(sEgoH2, lr, (kc+j)*64 + lg*16, 512);
      #pragma unroll
      for (int j = 0; j < 4; ++j)
        #pragma unroll
        for (int c2 = 0; c2 < 2; ++c2)
          slct[c2] = __builtin_amdgcn_mfma_f32_16x16x32_bf16(af[j], bfr[j][c2], slct[c2], 0, 0, 0);
    }
    slct[0] *= 0.125f;   // fold 1/sqrt(AD) into slct
    slct[1] *= 0.125f;
  }
  gemm_block<256, 3, 2, true>(sH1, 0, sAdo2, 0, ws + OFF_ADO1, ab1, w, lr, lg);
  __syncthreads();

  // ---- phase 5: ado0 agents 3..4 -> sH1 rows 0..31
  gemm_block<32, 2, 1, true>(sAdoIn, 48, sH1, 0, ws + OFF_ADO0, ab0, w, lr, lg);
  __syncthreads();

  // ---- phase 6: ado1 agents 3..4 -> sAdo2 rows 48..79 (C=2)
  gemm_block<256, 2, 2, true>(sH1, 0, sAdo2, 48, ws + OFF_ADO1, ab1, w, lr, lg);
  __syncthreads();

  // ---- phase 7a: key pass, c2-OUTER (kacc[5]=20 AGPR) with C=2 af/bk batches
  f32x4 part[5];
  #pragma unroll
  for (int n = 0; n < 5; ++n) part[n] = f32x4{0.f,0.f,0.f,0.f};
  {
    const __bf16* WK = ws + OFF_KEY;
    #pragma unroll
    for (int c2 = 0; c2 < 2; ++c2) {
      const int col = w*32 + c2*16 + lr;
      f32x4 kacc[5];
      #pragma unroll
      for (int n = 0; n < 5; ++n) kacc[n] = f32x4{0.f,0.f,0.f,0.f};
      #pragma unroll
      for (int kc = 0; kc < 8; kc += 2) {
        bf16x8 bk[2];
        #pragma unroll
        for (int j = 0; j < 2; ++j)
          bk[j] = *reinterpret_cast<const bf16x8*>(WK + col*256 + (kc+j)*32 + lg*8);
        bf16x8 af[2][5];
        #pragma unroll
        for (int j = 0; j < 2; ++j)
          #pragma unroll
          for (int n = 0; n < 5; ++n)
            af[j][n] = lds_loadA(sAdo2, n*16 + lr, (kc+j)*64 + lg*16, 512);
        #pragma unroll
        for (int j = 0; j < 2; ++j)
          #pragma unroll
          for (int n = 0; n < 5; ++n)
            kacc[n] = __builtin_amdgcn_mfma_f32_16x16x32_bf16(af[j][n], bk[j], kacc[n], 0, 0, 0);
      }
      #pragma unroll
      for (int n = 0; n < 5; ++n) part[n] += kacc[n] * slct[c2];
    }
  }
  // reduce over lr lanes (sum over this wave's 32 d-dims)
  #pragma unroll
  for (int n = 0; n < 5; ++n) {
    #pragma unroll
    for (int m = 1; m < 16; m <<= 1) {
      part[n][0] += __shfl_xor(part[n][0], m);
      part[n][1] += __shfl_xor(part[n][1], m);
      part[n][2] += __shfl_xor(part[n][2], m);
      part[n][3] += __shfl_xor(part[n][3], m);
    }
  }
  // publish wave partials: sLogF[w][n][row] (f32x4 per (w,n,lg))
  #pragma unroll
  for (int n = 0; n < 5; ++n)
    if (lr == n)
      *reinterpret_cast<f32x4*>(sLogF + (w*5 + n)*16 + lg*4) = part[n];
  __syncthreads();
  // full logits = own + partner partial; exact softmax in-place in part[]
  {
    #pragma unroll
    for (int n = 0; n < 5; ++n)
      part[n] = *reinterpret_cast<const f32x4*>(sLogF + (w*5 + n)*16 + lg*4)
              + *reinterpret_cast<const f32x4*>(sLogF + ((w^1)*5 + n)*16 + lg*4);
    f32x4 mx = part[0];
    #pragma unroll
    for (int n = 1; n < 5; ++n)
      #pragma unroll
      for (int e = 0; e < 4; ++e) mx[e] = fmaxf(mx[e], part[n][e]);
    f32x4 s = f32x4{0.f,0.f,0.f,0.f};
    #pragma unroll
    for (int n = 0; n < 5; ++n) {
      #pragma unroll
      for (int e = 0; e < 4; ++e) part[n][e] = __expf(part[n][e] - mx[e]);
      s += part[n];
    }
    f32x4 inv;
    #pragma unroll
    for (int e = 0; e < 4; ++e) inv[e] = 1.0f / s[e];
    #pragma unroll
    for (int n = 0; n < 5; ++n) part[n] *= inv;
  }

  // ---- phase 7b: lat pass, same c2-outer C=2 shape; agg in regs
  f32x4 agg[2];
  agg[0] = f32x4{0.f,0.f,0.f,0.f};
  agg[1] = f32x4{0.f,0.f,0.f,0.f};
  {
    const __bf16* WL = ws + OFF_LAT;
    #pragma unroll
    for (int c2 = 0; c2 < 2; ++c2) {
      const int col = w*32 + c2*16 + lr;
      f32x4 lacc[5];
      #pragma unroll
      for (int n = 0; n < 5; ++n) lacc[n] = f32x4{0.f,0.f,0.f,0.f};
      #pragma unroll
      for (int kc = 0; kc < 8; kc += 2) {
        bf16x8 bl[2];
        #pragma unroll
        for (int j = 0; j < 2; ++j)
          bl[j] = *reinterpret_cast<const bf16x8*>(WL + col*256 + (kc+j)*32 + lg*8);
        bf16x8 af[2][5];
        #pragma unroll
        for (int j = 0; j < 2; ++j)
          #pragma unroll
          for (int n = 0; n < 5; ++n)
            af[j][n] = lds_loadA(sAdo2, n*16 + lr, (kc+j)*64 + lg*16, 512);
        #pragma unroll
        for (int j = 0; j < 2; ++j)
          #pragma unroll
          for (int n = 0; n < 5; ++n)
            lacc[n] = __builtin_amdgcn_mfma_f32_16x16x32_bf16(af[j][n], bl[j], lacc[n], 0, 0, 0);
      }
      const float lb = latb[col];
      #pragma unroll
      for (int n = 0; n < 5; ++n) {
        #pragma unroll
        for (int e = 0; e < 4; ++e) {
          float x = lacc[n][e] + lb;
          x = x > 0.f ? x : 0.01f * x;
          agg[c2][e] += part[n][e] * x;
        }
      }
    }
  }
  // agg -> sProj (proj input, bf16 swz). Overwrites sEgoH2 (dead).
  #pragma unroll
  for (int c2 = 0; c2 < 2; ++c2)
    #pragma unroll
    for (int e = 0; e < 4; ++e)
      lds_store_bf16(sProj, lg*4 + e, w*32 + c2*16 + lr, (__bf16)agg[c2][e]);
  __syncthreads();

  // ---- phase 8: proj (16x256)@(256x64); waves 0..3 -> cols w*16..w*16+15
  if (w < 4) {
    const __bf16* WT = ws + OFF_PROJ;
    f32x4 pacc = f32x4{0.f,0.f,0.f,0.f};
    #pragma unroll
    for (int kc = 0; kc < 8; kc += 4) {
      bf16x8 bfr[4];
      #pragma unroll
      for (int j = 0; j < 4; ++j)
        bfr[j] = *reinterpret_cast<const bf16x8*>(WT + (w*16+lr)*256 + (kc+j)*32 + lg*8);
      bf16x8 af[4];
      #pragma unroll
      for (int j = 0; j < 4; ++j)
        af[j] = lds_loadA(sProj, lr, (kc+j)*64 + lg*16, 512);
      #pragma unroll
      for (int j = 0; j < 4; ++j)
        pacc = __builtin_amdgcn_mfma_f32_16x16x32_bf16(af[j], bfr[j], pacc, 0, 0, 0);
    }
    const float pb = projb[w*16 + lr];
    #pragma unroll
    for (int e = 0; e < 4; ++e)
      sOutF[(lg*4 + e)*64 + w*16 + lr] = pacc[e] + pb;
  }
  __syncthreads();

  // ---- phase 9: coalesced NT float4 writes of out[:, 48:112]
  if (tid < 256) {
    int row = tid >> 4, q = tid & 15;
    f32x4 v = *reinterpret_cast<const f32x4*>(sOutF + row*64 + q*4);
    __builtin_nontemporal_store(v,
        reinterpret_cast<f32x4*>(out + (size_t)(b0+row)*112 + 48 + q*4));
  }
}

extern "C" void kernel_launch(void* const* d_in, const int* in_sizes, int n_in,
                              void* d_out, int out_size, void* d_ws, size_t ws_size,
                              hipStream_t stream) {
  const float* obs   = (const float*)d_in[0];
  const float* ew0   = (const float*)d_in[1];
  const float* eb0   = (const float*)d_in[2];
  const float* ew1   = (const float*)d_in[3];
  const float* eb1   = (const float*)d_in[4];
  const float* aw0   = (const float*)d_in[5];
  const float* ab0   = (const float*)d_in[6];
  const float* aw1   = (const float*)d_in[7];
  const float* ab1   = (const float*)d_in[8];
  const float* keyw  = (const float*)d_in[9];
  const float* selw  = (const float*)d_in[10];
  const float* latw  = (const float*)d_in[11];
  const float* latb  = (const float*)d_in[12];
  const float* projw = (const float*)d_in[13];
  const float* projb = (const float*)d_in[14];
  __bf16* ws = (__bf16*)d_ws;
  float* out = (float*)d_out;

  prep_weights<<<dim3((WS_ELEMS + 255)/256), dim3(256), 0, stream>>>(
      ew0, ew1, aw0, aw1, keyw, selw, latw, projw, ws);
  fused_kernel<<<dim3(65536/16), dim3(512), 0, stream>>>(
      obs, eb0, eb1, ab0, ab1, latb, projb, ws, out);
}